// Round 4
// baseline (237.684 us; speedup 1.0000x reference)
//
#include <hip/hip_runtime.h>
#include <hip/hip_bf16.h>
#include <math.h>

#define Bv 8
#define Tv 32
#define Nv 500
#define Fin 64
#define Hv 128
#define Ev 8000
#define Kv 3
#define BT (Bv*Tv)      /* 256 */
#define ROWS (BT*Nv)    /* 128000 */
#define KK (Kv*Hv)      /* 384: flattened conv K dim */

/* k_mega LDS layout (shorts). Total 26760 shorts = 53520 B -> 53760 alloc
   -> 3 blocks/CU (161280 <= 163840). */
#define HROW 136        /* h row stride (272B) */
#define HS_NODE (32*HROW)   /* 4352 shorts per node: rows t=0..31 */
#define ZROW (4*HS_NODE)    /* 17408: single shared zero row (conv pad) */
#define AGS_BASE (ZROW+HROW)/* 17544 (x2B = 35088, 16B aligned) */
#define AGROW 72            /* AGG row stride (144B, 16B aligned) */
#define AGS_NODE (32*AGROW) /* 2304 shorts per node */
#define SMEM_SHORTS (AGS_BASE + 4*AGS_NODE)  /* 26760 */

typedef __attribute__((ext_vector_type(8))) short s8v;   // 8 bf16 = 4 VGPRs
typedef __attribute__((ext_vector_type(4))) float f4v;   // MFMA acc

// branch-free erf (Abramowitz-Stegun 7.1.26, |err| <= 1.5e-7): rcp + 5 FMA + v_exp.
__device__ __forceinline__ float gelu_exact(float v){
    float t  = v*0.70710678118654752440f;
    float ax = fabsf(t);
    float k  = __builtin_amdgcn_rcpf(fmaf(0.3275911f, ax, 1.0f));
    float p  = k*fmaf(k, fmaf(k, fmaf(k, fmaf(k, 1.061405429f, -1.453152027f),
                                      1.421413741f), -0.284496736f), 0.254829592f);
    float e  = __expf(-ax*ax);
    float er = fmaf(-p, e, 1.0f);           // erf(|t|)
    er = copysignf(er, t);
    return 0.5f*v*(1.0f + er);
}
__device__ __forceinline__ short f2bs(float f){
    union { __hip_bfloat16 h; short s; } u;
    u.h = __float2bfloat16(f);
    return u.s;
}
__device__ __forceinline__ float b2f(short s){
    union { unsigned int i; float f; } u;
    u.i = ((unsigned int)(unsigned short)s) << 16;
    return u.f;
}

// ---- fused: block 0 = graph prep; blocks [1,1000] = x fp32 -> bf16 convert
//      (SAME layout (bt,n,c) - no transpose, fully coalesced both sides);
//      tail 64 blocks = weight prep. ----
__global__ __launch_bounds__(1024) void k_xprep(const float* __restrict__ x,
        short* __restrict__ xb, const float* __restrict__ W,
        const float* __restrict__ Wg, const float* __restrict__ Wr,
        short* __restrict__ W2, short* __restrict__ Wgt, short* __restrict__ Wrt,
        const int* __restrict__ ei, const float* __restrict__ ew,
        float* __restrict__ dinv, int* __restrict__ offs,
        int* __restrict__ csrc, float* __restrict__ cw){
    __shared__ float sdeg[Nv];
    __shared__ int   scnt[Nv];
    __shared__ float sdv[Nv];
    __shared__ int   scur[Nv];
    __shared__ int   sa[512], sb[512];
    int bid = blockIdx.x;
    int tid = threadIdx.x;
    if (bid == 0){
        // ---- graph prep (1024 threads) ----
        if (tid < Nv){ sdeg[tid] = 1.0f; scnt[tid] = 0; }   // self-loop pre-added
        __syncthreads();
        for (int e = tid; e < Ev; e += 1024){
            int d = ei[Ev + e];
            atomicAdd(&sdeg[d], ew[e]);
            atomicAdd(&scnt[d], 1);
        }
        __syncthreads();
        int c = 0;
        if (tid < Nv){
            float d = sdeg[tid];
            float v = (d > 0.f) ? rsqrtf(d) : 0.f;
            sdv[tid] = v; dinv[tid] = v;
        }
        if (tid < 512){ c = (tid < Nv) ? scnt[tid] : 0; sa[tid] = c; }
        __syncthreads();
        int* s = sa; int* t = sb;
        for (int off = 1; off < 512; off <<= 1){
            int v = 0;
            if (tid < 512){ v = s[tid]; if (tid >= off) v += s[tid - off]; }
            if (tid < 512) t[tid] = v;
            __syncthreads();
            int* tmp = s; s = t; t = tmp;
        }
        if (tid < Nv){ int excl = s[tid] - c; offs[tid] = excl; scur[tid] = excl; }
        if (tid == 0) offs[Nv] = Ev;
        __syncthreads();
        for (int e = tid; e < Ev; e += 1024){
            int sn = ei[e], d = ei[Ev + e];
            int pos = atomicAdd(&scur[d], 1);
            csrc[pos] = sn;
            cw[pos] = sdv[sn]*ew[e]*sdv[d];
        }
    } else if (bid <= 1000){
        // ---- x fp32 -> bf16, identity layout: thread = 8 consecutive floats ----
        int gid = (bid-1)*1024 + tid;        // 1,024,000 threads total
        const float4* x4 = (const float4*)x;
        float4 va = x4[gid*2];
        float4 vb = x4[gid*2+1];
        s8v r;
        r[0]=f2bs(va.x); r[1]=f2bs(va.y); r[2]=f2bs(va.z); r[3]=f2bs(va.w);
        r[4]=f2bs(vb.x); r[5]=f2bs(vb.y); r[6]=f2bs(vb.z); r[7]=f2bs(vb.w);
        ((s8v*)xb)[gid] = r;
    } else {
        int idx = (bid - 1001)*1024 + tid;
        if (idx < Hv*Hv*Kv){
            int o = idx/(Hv*Kv);
            int rem = idx - o*(Hv*Kv);
            int i = rem/Kv, k = rem - i*Kv;
            W2[o*KK + k*Hv + i] = f2bs(W[idx]);           // W2[o][k*128+i]
        } else if (idx < Hv*Hv*Kv + Hv*64){
            int j = idx - Hv*Hv*Kv;
            int o = j >> 6, k = j & 63;
            Wgt[j] = f2bs(Wg[k*Hv + o]);                  // Wgt[o][k]
        } else if (idx < Hv*Hv*Kv + 2*Hv*64){
            int j = idx - Hv*Hv*Kv - Hv*64;
            int o = j >> 6, k = j & 63;
            Wrt[j] = f2bs(Wr[k*Hv + o]);                  // Wrt[o][k]
        }
    }
}

// ---- mega kernel:
//   phase A: 4-node-interleaved SpMM (4 independent gather chains in flight)
//            reading xb in its native (bt,n,c) layout -> LDS (ags)
//   stage:   GCN GEMM (K=64) -> GELU -> LDS (hs)
//   main:    temporal conv GEMM (K=384) + residual GEMM (K=64)
//            + bias+GELU+residual+LayerNorm -> out
// block = 4 waves, 4 nodes; wave w owns output channels [w*32, w*32+32).
// bid swizzle: b = bid&7 pins one 2MB xb b-stripe per XCD (round-robin
// dispatch) -> SpMM gather is per-XCD L2-resident. 250*8 = 2000, bijective.
// LDS 53520B -> 3 blocks/CU; launch_bounds(256,3) caps VGPR at 170 (natural
// was 104 -> no spill expected; verify FETCH_SIZE stays ~17MB).
__global__ __launch_bounds__(256, 3) void k_mega(
        const short* __restrict__ xb,
        const float* __restrict__ dinv, const int* __restrict__ offs,
        const int* __restrict__ csrc, const float* __restrict__ cw,
        const short* __restrict__ W2, const short* __restrict__ Wgt,
        const short* __restrict__ Wrt,
        const float* __restrict__ bg, const float* __restrict__ btm,
        const float* __restrict__ br, const float* __restrict__ lw,
        const float* __restrict__ lb, float* __restrict__ out){
    __shared__ short smem[SMEM_SHORTS];
    float (*red)[4][2] = (float(*)[4][2])&smem[AGS_BASE];  // overlap dead ags
    int tid  = threadIdx.x;
    int w    = tid >> 6;
    int lane = tid & 63;
    int quad = lane >> 4;
    int laneo = lane & 15;
    int bid = blockIdx.x;
    int b  = bid & 7;
    int n0 = (bid >> 3) * 4;
    int o_base = w*32;

    float bgv[2], bbv[2], brv[2], lwv[2], lbv[2];
    #pragma unroll
    for (int nt = 0; nt < 2; ++nt){
        int o = o_base + nt*16 + laneo;
        bgv[nt] = bg[o]; bbv[nt] = btm[o]; brv[nt] = br[o];
        lwv[nt] = lw[o]; lbv[nt] = lb[o];
    }

    // shared conv zero-row (rows -1 and 32 clamp here)
    if (tid < 16){
        s8v z = {0,0,0,0,0,0,0,0};
        *(s8v*)&smem[ZROW + tid*8] = z;
    }

    // ---- phase A: fused SpMM, 4 nodes interleaved. Thread (tr, c8) owns
    //      8 channels of t-row tr for all 4 nodes. Gathers: 8x128B segments
    //      per wave per edge, 4 independent chains in flight. ----
    {
        int tr = tid >> 3;          // t-row 0..31
        int c8 = tid & 7;           // channel chunk 0..7
        const short* xrow = xb + ((size_t)(b*Tv + tr)*Nv)*64 + c8*8;
        float acc[4][8];
        int eb[4], elen[4]; int M = 0;
        #pragma unroll
        for (int g = 0; g < 4; ++g){
            int n = n0 + g;
            float dv = dinv[n];
            float sw = dv*dv;
            s8v v = *(const s8v*)(xrow + n*64);
            #pragma unroll
            for (int q = 0; q < 8; ++q) acc[g][q] = sw * b2f(v[q]);
            eb[g] = offs[n];
            int l = offs[n+1] - eb[g];
            elen[g] = l;
            M = (l > M) ? l : M;
        }
        for (int it = 0; it < M; ++it){
            int sn[4]; float wv[4];
            #pragma unroll
            for (int g = 0; g < 4; ++g){
                bool p = it < elen[g];
                int idx = p ? (eb[g] + it) : 0;     // clamp to valid entry
                sn[g] = csrc[idx];
                wv[g] = p ? cw[idx] : 0.f;
            }
            s8v u[4];
            #pragma unroll
            for (int g = 0; g < 4; ++g)
                u[g] = *(const s8v*)(xrow + sn[g]*64);
            #pragma unroll
            for (int g = 0; g < 4; ++g)
                #pragma unroll
                for (int q = 0; q < 8; ++q)
                    acc[g][q] = fmaf(wv[g], b2f(u[g][q]), acc[g][q]);
        }
        #pragma unroll
        for (int g = 0; g < 4; ++g){
            s8v rr;
            #pragma unroll
            for (int q = 0; q < 8; ++q) rr[q] = f2bs(acc[g][q]);
            *(s8v*)&smem[AGS_BASE + g*AGS_NODE + tr*AGROW + c8*8] = rr;
        }
    }

    // GCN B fragments (K=64: 2 k-steps) - issue before barrier to overlap
    s8v bwg[2][2];
    #pragma unroll
    for (int nt = 0; nt < 2; ++nt){
        const short* wp = Wgt + (o_base + nt*16 + laneo)*64 + quad*8;
        bwg[nt][0] = *(const s8v*)wp;
        bwg[nt][1] = *(const s8v*)(wp + 32);
    }
    __syncthreads();

    // ---- stage: GCN GEMM per node from ags, GELU, write h to LDS ----
    for (int g = 0; g < 4; ++g){
        const short* ap = &smem[AGS_BASE + g*AGS_NODE];
        #pragma unroll
        for (int m = 0; m < 2; ++m){
            const short* arp = ap + (m*16 + laneo)*AGROW + quad*8;
            s8v a0 = *(const s8v*)arp;
            s8v a1 = *(const s8v*)(arp + 32);
            f4v h0 = {0.f,0.f,0.f,0.f}, h1 = {0.f,0.f,0.f,0.f};
            h0 = __builtin_amdgcn_mfma_f32_16x16x32_bf16(a0, bwg[0][0], h0, 0,0,0);
            h0 = __builtin_amdgcn_mfma_f32_16x16x32_bf16(a1, bwg[0][1], h0, 0,0,0);
            h1 = __builtin_amdgcn_mfma_f32_16x16x32_bf16(a0, bwg[1][0], h1, 0,0,0);
            h1 = __builtin_amdgcn_mfma_f32_16x16x32_bf16(a1, bwg[1][1], h1, 0,0,0);
            #pragma unroll
            for (int r = 0; r < 4; ++r){
                int t = m*16 + quad*4 + r;          // C layout: row=quad*4+r
                short* hrow = &smem[g*HS_NODE + t*HROW];
                hrow[o_base + laneo]      = f2bs(gelu_exact(h0[r] + bgv[0]));
                hrow[o_base + 16 + laneo] = f2bs(gelu_exact(h1[r] + bgv[1]));
            }
        }
    }

    // conv + residual B fragments (loaded late to cut peak VGPR in stage phase)
    s8v breg[2][12], bwr[2][2];
    #pragma unroll
    for (int nt = 0; nt < 2; ++nt){
        int o = o_base + nt*16 + laneo;
        const short* wp = W2 + o*KK + quad*8;
        #pragma unroll
        for (int s = 0; s < 12; ++s)
            breg[nt][s] = *(const s8v*)(wp + s*32);
        const short* wr = Wrt + o*64 + quad*8;
        bwr[nt][0] = *(const s8v*)wr;
        bwr[nt][1] = *(const s8v*)(wr + 32);
    }
    __syncthreads();

    for (int g = 0; g < 4; ++g){
        int n = n0 + g;
        // ---- temporal conv MFMA: 2 m-tiles x 12 K-steps x 2 n-tiles ----
        f4v acc[2][2];
        #pragma unroll
        for (int m = 0; m < 2; ++m)
            #pragma unroll
            for (int nt = 0; nt < 2; ++nt)
                acc[m][nt] = (f4v){0.f,0.f,0.f,0.f};
        #pragma unroll
        for (int m = 0; m < 2; ++m){
            #pragma unroll
            for (int s = 0; s < 12; ++s){
                int k  = s >> 2;
                int i0 = (s & 3) * 32;
                int row = m*16 + laneo + k - 1;     // true time index
                int hb = ((unsigned)row > 31u) ? ZROW : (g*HS_NODE + row*HROW);
                s8v a = *(const s8v*)&smem[hb + i0 + quad*8];
                acc[m][0] = __builtin_amdgcn_mfma_f32_16x16x32_bf16(a, breg[0][s], acc[m][0], 0,0,0);
                acc[m][1] = __builtin_amdgcn_mfma_f32_16x16x32_bf16(a, breg[1][s], acc[m][1], 0,0,0);
            }
        }
        // ---- residual GEMM from xb rows (same C layout -> register add) ----
        f4v racc[2][2];
        #pragma unroll
        for (int m = 0; m < 2; ++m)
            #pragma unroll
            for (int nt = 0; nt < 2; ++nt)
                racc[m][nt] = (f4v){0.f,0.f,0.f,0.f};
        #pragma unroll
        for (int m = 0; m < 2; ++m){
            const short* xrp = xb + ((size_t)(b*Tv + m*16 + laneo)*Nv + n)*64 + quad*8;
            s8v a0 = *(const s8v*)xrp;
            s8v a1 = *(const s8v*)(xrp + 32);
            racc[m][0] = __builtin_amdgcn_mfma_f32_16x16x32_bf16(a0, bwr[0][0], racc[m][0], 0,0,0);
            racc[m][0] = __builtin_amdgcn_mfma_f32_16x16x32_bf16(a1, bwr[0][1], racc[m][0], 0,0,0);
            racc[m][1] = __builtin_amdgcn_mfma_f32_16x16x32_bf16(a0, bwr[1][0], racc[m][1], 0,0,0);
            racc[m][1] = __builtin_amdgcn_mfma_f32_16x16x32_bf16(a1, bwr[1][1], racc[m][1], 0,0,0);
        }
        // ---- epilogue: bias+GELU+residual, LN stats ----
        size_t obase = ((size_t)b*Tv*Nv + n)*Hv;
        float yv[2][2][4];
        float srow[2][4], ssrow[2][4];
        #pragma unroll
        for (int m = 0; m < 2; ++m)
            #pragma unroll
            for (int r = 0; r < 4; ++r){ srow[m][r] = 0.f; ssrow[m][r] = 0.f; }
        #pragma unroll
        for (int m = 0; m < 2; ++m){
            #pragma unroll
            for (int nt = 0; nt < 2; ++nt){
                #pragma unroll
                for (int r = 0; r < 4; ++r){
                    float gv = gelu_exact(acc[m][nt][r] + bbv[nt]);
                    float y = gv + racc[m][nt][r] + brv[nt];
                    yv[m][nt][r] = y;
                    srow[m][r] += y; ssrow[m][r] += y*y;
                }
            }
        }
        #pragma unroll
        for (int m = 0; m < 2; ++m)
            #pragma unroll
            for (int r = 0; r < 4; ++r){
                #pragma unroll
                for (int msk = 8; msk >= 1; msk >>= 1){
                    srow[m][r]  += __shfl_xor(srow[m][r],  msk, 64);
                    ssrow[m][r] += __shfl_xor(ssrow[m][r], msk, 64);
                }
            }
        if (laneo == 0){
            #pragma unroll
            for (int m = 0; m < 2; ++m)
                #pragma unroll
                for (int r = 0; r < 4; ++r){
                    int t = m*16 + quad*4 + r;
                    red[t][w][0] = srow[m][r];
                    red[t][w][1] = ssrow[m][r];
                }
        }
        __syncthreads();
        #pragma unroll
        for (int m = 0; m < 2; ++m){
            #pragma unroll
            for (int r = 0; r < 4; ++r){
                int t = m*16 + quad*4 + r;
                float s  = red[t][0][0] + red[t][1][0] + red[t][2][0] + red[t][3][0];
                float ss = red[t][0][1] + red[t][1][1] + red[t][2][1] + red[t][3][1];
                float mu = s * (1.f/128.f);
                float var = fmaxf(ss * (1.f/128.f) - mu*mu, 0.f);
                float rstd = rsqrtf(var + 1e-5f);
                #pragma unroll
                for (int nt = 0; nt < 2; ++nt){
                    int o = o_base + nt*16 + laneo;
                    out[obase + (size_t)t*Nv*Hv + o] =
                        (yv[m][nt][r] - mu)*rstd*lwv[nt] + lbv[nt];
                }
            }
        }
        __syncthreads();
    }
}

extern "C" void kernel_launch(void* const* d_in, const int* in_sizes, int n_in,
                              void* d_out, int out_size, void* d_ws, size_t ws_size,
                              hipStream_t stream){
    const float* x   = (const float*)d_in[0];
    const int*   ei  = (const int*)d_in[1];
    const float* ew  = (const float*)d_in[2];
    const float* Wg  = (const float*)d_in[3];
    const float* bg  = (const float*)d_in[4];
    const float* Wtm = (const float*)d_in[5];
    const float* btm = (const float*)d_in[6];
    const float* lw  = (const float*)d_in[7];
    const float* lb  = (const float*)d_in[8];
    const float* Wr  = (const float*)d_in[9];
    const float* br  = (const float*)d_in[10];
    float* out = (float*)d_out;

    char* ws = (char*)d_ws;
    float* dinv = (float*)(ws + 0);            // 2048 B
    int*   offs = (int*)  (ws + 4096);         // 2048 B
    int*   csrc = (int*)  (ws + 8192);         // 32768 B
    float* cwn  = (float*)(ws + 40960);        // 32768 B
    short* W2   = (short*)(ws + 73728);        // 98304 B
    short* Wgt  = (short*)(ws + 172032);       // 16384 B
    short* Wrt  = (short*)(ws + 188416);       // 16384 B
    short* xb   = (short*)(ws + 204800);       // 16.384 MB (bf16 x, same layout)

    k_xprep<<<1 + 1000 + 64, 1024, 0, stream>>>(x, xb, Wtm, Wg, Wr,
                                                W2, Wgt, Wrt,
                                                ei, ew, dinv, offs, csrc, cwn);
    k_mega <<<(Bv*Nv)/4, 256, 0, stream>>>(xb, dinv, offs, csrc, cwn,
                                           W2, Wgt, Wrt,
                                           bg, btm, br, lw, lb, out);
}

// Round 5
// 228.284 us; speedup vs baseline: 1.0412x; 1.0412x over previous
//
#include <hip/hip_runtime.h>
#include <hip/hip_bf16.h>
#include <math.h>

#define Bv 8
#define Tv 32
#define Nv 500
#define Fin 64
#define Hv 128
#define Ev 8000
#define Kv 3
#define BT (Bv*Tv)      /* 256 */
#define ROWS (BT*Nv)    /* 128000 */
#define KK (Kv*Hv)      /* 384: flattened conv K dim */

/* k_mega LDS layout (shorts). Total 26760 shorts = 53520 B.
   hs region [0, 17408) is dead until the stage phase -> graph-prep overlay
   (sdeg/ecnt/esrc/ewt, 10208 B) lives there during phase A. */
#define HROW 136            /* h row stride (272B): 2-way bank phase on A-reads */
#define HS_NODE (32*HROW)   /* 4352 shorts per node: rows t=0..31 */
#define ZROW (4*HS_NODE)    /* 17408: single shared zero row (conv pad) */
#define AGS_BASE (ZROW+HROW)/* 17544 shorts (35088 B, 16B aligned) */
#define AGROW 72            /* AGG row stride (144B, 16B aligned) */
#define AGS_NODE (32*AGROW) /* 2304 shorts per node */
#define SMEM_SHORTS (AGS_BASE + 4*AGS_NODE)  /* 26760 */
#define EMAX 256            /* per-node edge-list capacity (mean deg 16) */

typedef __attribute__((ext_vector_type(8))) short s8v;   // 8 bf16 = 4 VGPRs
typedef __attribute__((ext_vector_type(4))) float f4v;   // MFMA acc

// branch-free erf (Abramowitz-Stegun 7.1.26, |err| <= 1.5e-7): rcp + 5 FMA + v_exp.
__device__ __forceinline__ float gelu_exact(float v){
    float t  = v*0.70710678118654752440f;
    float ax = fabsf(t);
    float k  = __builtin_amdgcn_rcpf(fmaf(0.3275911f, ax, 1.0f));
    float p  = k*fmaf(k, fmaf(k, fmaf(k, fmaf(k, 1.061405429f, -1.453152027f),
                                      1.421413741f), -0.284496736f), 0.254829592f);
    float e  = __expf(-ax*ax);
    float er = fmaf(-p, e, 1.0f);           // erf(|t|)
    er = copysignf(er, t);
    return 0.5f*v*(1.0f + er);
}
__device__ __forceinline__ short f2bs(float f){
    union { __hip_bfloat16 h; short s; } u;
    u.h = __float2bfloat16(f);
    return u.s;
}
__device__ __forceinline__ float b2f(short s){
    union { unsigned int i; float f; } u;
    u.i = ((unsigned int)(unsigned short)s) << 16;
    return u.f;
}

// ---- trivial pre-kernel: x fp32 -> bf16 (identity layout, coalesced both
//      sides) + weight repacks. No graph work - that moved into k_mega. ----
__global__ __launch_bounds__(1024) void k_conv(const float* __restrict__ x,
        short* __restrict__ xb, const float* __restrict__ W,
        const float* __restrict__ Wg, const float* __restrict__ Wr,
        short* __restrict__ W2, short* __restrict__ Wgt, short* __restrict__ Wrt){
    int bid = blockIdx.x;
    int tid = threadIdx.x;
    if (bid < 1000){
        int gid = bid*1024 + tid;            // 1,024,000 threads: 8 floats each
        const float4* x4 = (const float4*)x;
        float4 va = x4[gid*2];
        float4 vb = x4[gid*2+1];
        s8v r;
        r[0]=f2bs(va.x); r[1]=f2bs(va.y); r[2]=f2bs(va.z); r[3]=f2bs(va.w);
        r[4]=f2bs(vb.x); r[5]=f2bs(vb.y); r[6]=f2bs(vb.z); r[7]=f2bs(vb.w);
        ((s8v*)xb)[gid] = r;
    } else {
        int idx = (bid - 1000)*1024 + tid;
        if (idx < Hv*Hv*Kv){
            int o = idx/(Hv*Kv);
            int rem = idx - o*(Hv*Kv);
            int i = rem/Kv, k = rem - i*Kv;
            W2[o*KK + k*Hv + i] = f2bs(W[idx]);           // W2[o][k*128+i]
        } else if (idx < Hv*Hv*Kv + Hv*64){
            int j = idx - Hv*Hv*Kv;
            int o = j >> 6, k = j & 63;
            Wgt[j] = f2bs(Wg[k*Hv + o]);                  // Wgt[o][k]
        } else if (idx < Hv*Hv*Kv + 2*Hv*64){
            int j = idx - Hv*Hv*Kv - Hv*64;
            int o = j >> 6, k = j & 63;
            Wrt[j] = f2bs(Wr[k*Hv + o]);                  // Wrt[o][k]
        }
    }
}

// ---- mega kernel, now fully self-contained:
//   prep:    per-block graph scan (96KB edge data, L2-broadcast): LDS degree
//            accumulate -> rsqrt -> per-node edge lists + norm weights
//   phase A: 4-node-interleaved SpMM from xb (native layout) -> LDS (ags)
//   stage:   GCN GEMM (K=64) -> GELU -> LDS (hs)
//   main:    temporal conv GEMM (K=384) + residual GEMM (K=64)
//            + bias+GELU+residual+LayerNorm -> out
// block = 4 waves, 4 nodes; wave w owns output channels [w*32, w*32+32).
// bid swizzle: b = bid&7 pins one 2MB xb b-stripe per XCD. 250*8=2000 bijective.
// launch_bounds(256,2): round-2/round-4 showed any tighter bound spills
// (phase-A live set + 96-reg conv-weight block needs the 256-reg budget).
__global__ __launch_bounds__(256, 2) void k_mega(
        const short* __restrict__ xb,
        const int* __restrict__ ei, const float* __restrict__ ew,
        const short* __restrict__ W2, const short* __restrict__ Wgt,
        const short* __restrict__ Wrt,
        const float* __restrict__ bg, const float* __restrict__ btm,
        const float* __restrict__ br, const float* __restrict__ lw,
        const float* __restrict__ lb, float* __restrict__ out){
    __shared__ short smem[SMEM_SHORTS];
    // prep overlay inside hs region (dead until stage phase):
    float* sdeg = (float*)&smem[0];          // 500 f  [0,2000)B ; becomes dinv
    int*   ecnt = (int*)  &smem[1000];       // 4 i    [2000,2016)B
    int*   esrc = (int*)  &smem[1008];       // 4*EMAX i [2016,6112)B
    float* ewt  = (float*)&smem[3056];       // 4*EMAX f [6112,10208)B
    float (*red)[4][2] = (float(*)[4][2])&smem[AGS_BASE];  // overlap dead ags
    int tid  = threadIdx.x;
    int w    = tid >> 6;
    int lane = tid & 63;
    int quad = lane >> 4;
    int laneo = lane & 15;
    int bid = blockIdx.x;
    int b  = bid & 7;
    int n0 = (bid >> 3) * 4;
    int o_base = w*32;

    // ---- prep: degree + per-node edge lists ----
    for (int i = tid; i < Nv; i += 256) sdeg[i] = 1.0f;  // self-loop pre-added
    if (tid < 4) ecnt[tid] = 0;
    if (tid < 16){
        s8v z = {0,0,0,0,0,0,0,0};
        *(s8v*)&smem[ZROW + tid*8] = z;      // shared conv zero-row
    }
    __syncthreads();
    for (int e = tid; e < Ev; e += 256){
        int sn = ei[e], dn = ei[Ev + e];
        float we = ew[e];
        atomicAdd(&sdeg[dn], we);
        int g = dn - n0;
        if ((unsigned)g < 4u){
            int pos = atomicAdd(&ecnt[g], 1);
            if (pos < EMAX){ esrc[g*EMAX + pos] = sn; ewt[g*EMAX + pos] = we; }
        }
    }
    __syncthreads();
    for (int i = tid; i < Nv; i += 256){
        float d = sdeg[i];
        sdeg[i] = (d > 0.f) ? rsqrtf(d) : 0.f;           // in-place -> dinv
    }
    __syncthreads();
    for (int j = tid; j < 4*EMAX; j += 256){
        int g = j >> 8;
        int i = j & (EMAX-1);
        int l = ecnt[g]; if (l > EMAX) l = EMAX;
        if (i < l) ewt[j] = ewt[j] * sdeg[esrc[j]] * sdeg[n0 + g];
    }
    __syncthreads();

    float bgv[2], bbv[2], brv[2], lwv[2], lbv[2];
    #pragma unroll
    for (int nt = 0; nt < 2; ++nt){
        int o = o_base + nt*16 + laneo;
        bgv[nt] = bg[o]; bbv[nt] = btm[o]; brv[nt] = br[o];
        lwv[nt] = lw[o]; lbv[nt] = lb[o];
    }

    // ---- phase A: fused SpMM, 4 nodes interleaved (4 chains in flight).
    //      Thread (tr,c8) owns 8 channels of t-row tr for all 4 nodes. ----
    {
        int tr = tid >> 3;          // t-row 0..31
        int c8 = tid & 7;           // channel chunk 0..7
        const short* xrow = xb + ((size_t)(b*Tv + tr)*Nv)*64 + c8*8;
        float acc[4][8];
        int elen[4]; int M = 0;
        #pragma unroll
        for (int g = 0; g < 4; ++g){
            float dv = sdeg[n0 + g];
            float sw = dv*dv;
            s8v v = *(const s8v*)(xrow + (n0 + g)*64);
            #pragma unroll
            for (int q = 0; q < 8; ++q) acc[g][q] = sw * b2f(v[q]);
            int l = ecnt[g]; if (l > EMAX) l = EMAX;
            elen[g] = l;
            M = (l > M) ? l : M;
        }
        for (int it = 0; it < M; ++it){
            int sn[4]; float wv[4];
            #pragma unroll
            for (int g = 0; g < 4; ++g){
                if (it < elen[g]){          // block-uniform branch
                    sn[g] = esrc[g*EMAX + it];   // LDS broadcast
                    wv[g] = ewt[g*EMAX + it];
                } else { sn[g] = n0; wv[g] = 0.f; }
            }
            s8v u[4];
            #pragma unroll
            for (int g = 0; g < 4; ++g)
                u[g] = *(const s8v*)(xrow + sn[g]*64);
            #pragma unroll
            for (int g = 0; g < 4; ++g)
                #pragma unroll
                for (int q = 0; q < 8; ++q)
                    acc[g][q] = fmaf(wv[g], b2f(u[g][q]), acc[g][q]);
        }
        #pragma unroll
        for (int g = 0; g < 4; ++g){
            s8v rr;
            #pragma unroll
            for (int q = 0; q < 8; ++q) rr[q] = f2bs(acc[g][q]);
            *(s8v*)&smem[AGS_BASE + g*AGS_NODE + tr*AGROW + c8*8] = rr;
        }
    }

    // GCN B fragments (K=64: 2 k-steps) - issue before barrier to overlap
    s8v bwg[2][2];
    #pragma unroll
    for (int nt = 0; nt < 2; ++nt){
        const short* wp = Wgt + (o_base + nt*16 + laneo)*64 + quad*8;
        bwg[nt][0] = *(const s8v*)wp;
        bwg[nt][1] = *(const s8v*)(wp + 32);
    }
    __syncthreads();

    // ---- stage: GCN GEMM per node from ags, GELU, write h to LDS ----
    for (int g = 0; g < 4; ++g){
        const short* ap = &smem[AGS_BASE + g*AGS_NODE];
        #pragma unroll
        for (int m = 0; m < 2; ++m){
            const short* arp = ap + (m*16 + laneo)*AGROW + quad*8;
            s8v a0 = *(const s8v*)arp;
            s8v a1 = *(const s8v*)(arp + 32);
            f4v h0 = {0.f,0.f,0.f,0.f}, h1 = {0.f,0.f,0.f,0.f};
            h0 = __builtin_amdgcn_mfma_f32_16x16x32_bf16(a0, bwg[0][0], h0, 0,0,0);
            h0 = __builtin_amdgcn_mfma_f32_16x16x32_bf16(a1, bwg[0][1], h0, 0,0,0);
            h1 = __builtin_amdgcn_mfma_f32_16x16x32_bf16(a0, bwg[1][0], h1, 0,0,0);
            h1 = __builtin_amdgcn_mfma_f32_16x16x32_bf16(a1, bwg[1][1], h1, 0,0,0);
            #pragma unroll
            for (int r = 0; r < 4; ++r){
                int t = m*16 + quad*4 + r;          // C layout: row=quad*4+r
                short* hrow = &smem[g*HS_NODE + t*HROW];
                hrow[o_base + laneo]      = f2bs(gelu_exact(h0[r] + bgv[0]));
                hrow[o_base + 16 + laneo] = f2bs(gelu_exact(h1[r] + bgv[1]));
            }
        }
    }

    // conv + residual B fragments (loaded late to cut peak VGPR in stage phase)
    s8v breg[2][12], bwr[2][2];
    #pragma unroll
    for (int nt = 0; nt < 2; ++nt){
        int o = o_base + nt*16 + laneo;
        const short* wp = W2 + o*KK + quad*8;
        #pragma unroll
        for (int s = 0; s < 12; ++s)
            breg[nt][s] = *(const s8v*)(wp + s*32);
        const short* wr = Wrt + o*64 + quad*8;
        bwr[nt][0] = *(const s8v*)wr;
        bwr[nt][1] = *(const s8v*)(wr + 32);
    }
    __syncthreads();

    for (int g = 0; g < 4; ++g){
        int n = n0 + g;
        // ---- temporal conv MFMA: 2 m-tiles x 12 K-steps x 2 n-tiles ----
        f4v acc[2][2];
        #pragma unroll
        for (int m = 0; m < 2; ++m)
            #pragma unroll
            for (int nt = 0; nt < 2; ++nt)
                acc[m][nt] = (f4v){0.f,0.f,0.f,0.f};
        #pragma unroll
        for (int m = 0; m < 2; ++m){
            #pragma unroll
            for (int s = 0; s < 12; ++s){
                int k  = s >> 2;
                int i0 = (s & 3) * 32;
                int row = m*16 + laneo + k - 1;     // true time index
                int hb = ((unsigned)row > 31u) ? ZROW : (g*HS_NODE + row*HROW);
                s8v a = *(const s8v*)&smem[hb + i0 + quad*8];
                acc[m][0] = __builtin_amdgcn_mfma_f32_16x16x32_bf16(a, breg[0][s], acc[m][0], 0,0,0);
                acc[m][1] = __builtin_amdgcn_mfma_f32_16x16x32_bf16(a, breg[1][s], acc[m][1], 0,0,0);
            }
        }
        // ---- residual GEMM from xb rows (same C layout -> register add) ----
        f4v racc[2][2];
        #pragma unroll
        for (int m = 0; m < 2; ++m)
            #pragma unroll
            for (int nt = 0; nt < 2; ++nt)
                racc[m][nt] = (f4v){0.f,0.f,0.f,0.f};
        #pragma unroll
        for (int m = 0; m < 2; ++m){
            const short* xrp = xb + ((size_t)(b*Tv + m*16 + laneo)*Nv + n)*64 + quad*8;
            s8v a0 = *(const s8v*)xrp;
            s8v a1 = *(const s8v*)(xrp + 32);
            racc[m][0] = __builtin_amdgcn_mfma_f32_16x16x32_bf16(a0, bwr[0][0], racc[m][0], 0,0,0);
            racc[m][0] = __builtin_amdgcn_mfma_f32_16x16x32_bf16(a1, bwr[0][1], racc[m][0], 0,0,0);
            racc[m][1] = __builtin_amdgcn_mfma_f32_16x16x32_bf16(a0, bwr[1][0], racc[m][1], 0,0,0);
            racc[m][1] = __builtin_amdgcn_mfma_f32_16x16x32_bf16(a1, bwr[1][1], racc[m][1], 0,0,0);
        }
        // ---- epilogue: bias+GELU+residual, LN stats ----
        size_t obase = ((size_t)b*Tv*Nv + n)*Hv;
        float yv[2][2][4];
        float srow[2][4], ssrow[2][4];
        #pragma unroll
        for (int m = 0; m < 2; ++m)
            #pragma unroll
            for (int r = 0; r < 4; ++r){ srow[m][r] = 0.f; ssrow[m][r] = 0.f; }
        #pragma unroll
        for (int m = 0; m < 2; ++m){
            #pragma unroll
            for (int nt = 0; nt < 2; ++nt){
                #pragma unroll
                for (int r = 0; r < 4; ++r){
                    float gv = gelu_exact(acc[m][nt][r] + bbv[nt]);
                    float y = gv + racc[m][nt][r] + brv[nt];
                    yv[m][nt][r] = y;
                    srow[m][r] += y; ssrow[m][r] += y*y;
                }
            }
        }
        #pragma unroll
        for (int m = 0; m < 2; ++m)
            #pragma unroll
            for (int r = 0; r < 4; ++r){
                #pragma unroll
                for (int msk = 8; msk >= 1; msk >>= 1){
                    srow[m][r]  += __shfl_xor(srow[m][r],  msk, 64);
                    ssrow[m][r] += __shfl_xor(ssrow[m][r], msk, 64);
                }
            }
        if (laneo == 0){
            #pragma unroll
            for (int m = 0; m < 2; ++m)
                #pragma unroll
                for (int r = 0; r < 4; ++r){
                    int t = m*16 + quad*4 + r;
                    red[t][w][0] = srow[m][r];
                    red[t][w][1] = ssrow[m][r];
                }
        }
        __syncthreads();
        #pragma unroll
        for (int m = 0; m < 2; ++m){
            #pragma unroll
            for (int r = 0; r < 4; ++r){
                int t = m*16 + quad*4 + r;
                float s  = red[t][0][0] + red[t][1][0] + red[t][2][0] + red[t][3][0];
                float ss = red[t][0][1] + red[t][1][1] + red[t][2][1] + red[t][3][1];
                float mu = s * (1.f/128.f);
                float var = fmaxf(ss * (1.f/128.f) - mu*mu, 0.f);
                float rstd = rsqrtf(var + 1e-5f);
                #pragma unroll
                for (int nt = 0; nt < 2; ++nt){
                    int o = o_base + nt*16 + laneo;
                    out[obase + (size_t)t*Nv*Hv + o] =
                        (yv[m][nt][r] - mu)*rstd*lwv[nt] + lbv[nt];
                }
            }
        }
        __syncthreads();
    }
}

extern "C" void kernel_launch(void* const* d_in, const int* in_sizes, int n_in,
                              void* d_out, int out_size, void* d_ws, size_t ws_size,
                              hipStream_t stream){
    const float* x   = (const float*)d_in[0];
    const int*   ei  = (const int*)d_in[1];
    const float* ew  = (const float*)d_in[2];
    const float* Wg  = (const float*)d_in[3];
    const float* bg  = (const float*)d_in[4];
    const float* Wtm = (const float*)d_in[5];
    const float* btm = (const float*)d_in[6];
    const float* lw  = (const float*)d_in[7];
    const float* lb  = (const float*)d_in[8];
    const float* Wr  = (const float*)d_in[9];
    const float* br  = (const float*)d_in[10];
    float* out = (float*)d_out;

    char* ws = (char*)d_ws;
    short* W2   = (short*)(ws + 0);            // 98304 B
    short* Wgt  = (short*)(ws + 98304);        // 16384 B
    short* Wrt  = (short*)(ws + 114688);       // 16384 B
    short* xb   = (short*)(ws + 131072);       // 16.384 MB (bf16 x, same layout)

    k_conv<<<1000 + 64, 1024, 0, stream>>>(x, xb, Wtm, Wg, Wr, W2, Wgt, Wrt);
    k_mega<<<(Bv*Nv)/4, 256, 0, stream>>>(xb, ei, ew, W2, Wgt, Wrt,
                                          bg, btm, br, lw, lb, out);
}

// Round 6
// 218.515 us; speedup vs baseline: 1.0877x; 1.0447x over previous
//
#include <hip/hip_runtime.h>
#include <hip/hip_bf16.h>
#include <math.h>

#define Bv 8
#define Tv 32
#define Nv 500
#define Fin 64
#define Hv 128
#define Ev 8000
#define Kv 3
#define BT (Bv*Tv)      /* 256 */
#define ROWS (BT*Nv)    /* 128000 */
#define KK (Kv*Hv)      /* 384: flattened conv K dim */

/* k_mega LDS layout (shorts), ONE node per block. 6792 shorts = 13584 B. */
#define HROW 136            /* h row stride (272B) */
#define ZROW (32*HROW)      /* 4352: single zero row (conv pad) */
#define AGS_BASE (ZROW+HROW)/* 4488 shorts (8976 B, 16B aligned) */
#define AGROW 72            /* AGG row stride (144B, 16B aligned) */
#define SMEM_SHORTS (AGS_BASE + 32*AGROW)  /* 6792 */

typedef __attribute__((ext_vector_type(8))) short s8v;   // 8 bf16 = 4 VGPRs
typedef __attribute__((ext_vector_type(4))) float f4v;   // MFMA acc

// branch-free erf (Abramowitz-Stegun 7.1.26, |err| <= 1.5e-7): rcp + 5 FMA + v_exp.
__device__ __forceinline__ float gelu_exact(float v){
    float t  = v*0.70710678118654752440f;
    float ax = fabsf(t);
    float k  = __builtin_amdgcn_rcpf(fmaf(0.3275911f, ax, 1.0f));
    float p  = k*fmaf(k, fmaf(k, fmaf(k, fmaf(k, 1.061405429f, -1.453152027f),
                                      1.421413741f), -0.284496736f), 0.254829592f);
    float e  = __expf(-ax*ax);
    float er = fmaf(-p, e, 1.0f);           // erf(|t|)
    er = copysignf(er, t);
    return 0.5f*v*(1.0f + er);
}
__device__ __forceinline__ short f2bs(float f){
    union { __hip_bfloat16 h; short s; } u;
    u.h = __float2bfloat16(f);
    return u.s;
}
__device__ __forceinline__ float b2f(short s){
    union { unsigned int i; float f; } u;
    u.i = ((unsigned int)(unsigned short)s) << 16;
    return u.f;
}

// ---- fused: block 0 = graph prep (degree+counts, scan, CSR fill);
//      blocks [1, 2000] = x transpose to bf16; tail 64 blocks = weight prep. ----
__global__ __launch_bounds__(1024) void k_xprep(const float* __restrict__ x,
        short* __restrict__ X2b, const float* __restrict__ W,
        const float* __restrict__ Wg, const float* __restrict__ Wr,
        short* __restrict__ W2, short* __restrict__ Wgt, short* __restrict__ Wrt,
        const int* __restrict__ ei, const float* __restrict__ ew,
        float* __restrict__ dinv, int* __restrict__ offs,
        int* __restrict__ csrc, float* __restrict__ cw){
    __shared__ float sdeg[Nv];
    __shared__ int   scnt[Nv];
    __shared__ float sdv[Nv];
    __shared__ int   scur[Nv];
    __shared__ int   sa[512], sb[512];
    int bid = blockIdx.x;
    int tid = threadIdx.x;
    if (bid == 0){
        // ---- graph prep (1024 threads) ----
        if (tid < Nv){ sdeg[tid] = 1.0f; scnt[tid] = 0; }   // self-loop pre-added
        __syncthreads();
        for (int e = tid; e < Ev; e += 1024){
            int d = ei[Ev + e];
            atomicAdd(&sdeg[d], ew[e]);
            atomicAdd(&scnt[d], 1);
        }
        __syncthreads();
        int c = 0;
        if (tid < Nv){
            float d = sdeg[tid];
            float v = (d > 0.f) ? rsqrtf(d) : 0.f;
            sdv[tid] = v; dinv[tid] = v;
        }
        if (tid < 512){ c = (tid < Nv) ? scnt[tid] : 0; sa[tid] = c; }
        __syncthreads();
        int* s = sa; int* t = sb;
        for (int off = 1; off < 512; off <<= 1){
            int v = 0;
            if (tid < 512){ v = s[tid]; if (tid >= off) v += s[tid - off]; }
            if (tid < 512) t[tid] = v;
            __syncthreads();
            int* tmp = s; s = t; t = tmp;
        }
        if (tid < Nv){ int excl = s[tid] - c; offs[tid] = excl; scur[tid] = excl; }
        if (tid == 0) offs[Nv] = Ev;
        __syncthreads();
        for (int e = tid; e < Ev; e += 1024){
            int sn = ei[e], d = ei[Ev + e];
            int pos = atomicAdd(&scur[d], 1);
            csrc[pos] = sn;
            cw[pos] = sdv[sn]*ew[e]*sdv[d];
        }
    } else if (bid <= ROWS/64){
        // ---- x (bt,n,c) fp32 -> X2b (n, bt*64+c) bf16 ----
        int gid = (bid-1)*1024 + tid;        // one float4; total ROWS*16
        int row = gid >> 4, c4 = gid & 15;
        int bt = row / Nv;
        int n  = row - bt*Nv;
        float4 v = ((const float4*)x)[gid];
        short4 sv;
        sv.x = f2bs(v.x); sv.y = f2bs(v.y); sv.z = f2bs(v.z); sv.w = f2bs(v.w);
        *(short4*)(X2b + (size_t)n*(BT*64) + bt*64 + c4*4) = sv;
    } else {
        int idx = (bid - 1 - ROWS/64)*1024 + tid;
        if (idx < Hv*Hv*Kv){
            int o = idx/(Hv*Kv);
            int rem = idx - o*(Hv*Kv);
            int i = rem/Kv, k = rem - i*Kv;
            W2[o*KK + k*Hv + i] = f2bs(W[idx]);           // W2[o][k*128+i]
        } else if (idx < Hv*Hv*Kv + Hv*64){
            int j = idx - Hv*Hv*Kv;
            int o = j >> 6, k = j & 63;
            Wgt[j] = f2bs(Wg[k*Hv + o]);                  // Wgt[o][k]
        } else if (idx < Hv*Hv*Kv + 2*Hv*64){
            int j = idx - Hv*Hv*Kv - Hv*64;
            int o = j >> 6, k = j & 63;
            Wrt[j] = f2bs(Wr[k*Hv + o]);                  // Wrt[o][k]
        }
    }
}

// ---- mega kernel, ONE node per block (grid 8*500 = 4000):
//   phase A: SpMM for this node's (32t x 64c) window, edge loop unrolled x4
//            with 4 independent accumulators (4 gather chains in flight)
//   stage:   GCN GEMM (K=64) -> GELU -> LDS (hs)
//   main:    temporal conv GEMM (K=384) + residual GEMM (K=64)
//            + bias+GELU+residual+LayerNorm -> out
// block = 4 waves; wave w owns output channels [w*32, w*32+32).
// bid swizzle: b = bid&7 pins one 2MB X2b b-stripe per XCD (round-robin
// dispatch). 500*8 = 4000, bijective.
// 4000 blocks / (~3-4 blocks/CU * 256 CU) = 4-5 residency rounds -> inter-block
// latency hiding, which the 500-block version (1 round, wall = serial chain)
// never had. NO tighter launch_bounds: rounds 2/4 proved any VGPR cap spills.
__global__ __launch_bounds__(256, 2) void k_mega(
        const short* __restrict__ X2b,
        const float* __restrict__ dinv, const int* __restrict__ offs,
        const int* __restrict__ csrc, const float* __restrict__ cw,
        const short* __restrict__ W2, const short* __restrict__ Wgt,
        const short* __restrict__ Wrt,
        const float* __restrict__ bg, const float* __restrict__ btm,
        const float* __restrict__ br, const float* __restrict__ lw,
        const float* __restrict__ lb, float* __restrict__ out){
    __shared__ short smem[SMEM_SHORTS];
    float (*red)[4][2] = (float(*)[4][2])&smem[AGS_BASE];  // overlay dead ags
    int tid  = threadIdx.x;
    int w    = tid >> 6;
    int lane = tid & 63;
    int quad = lane >> 4;
    int laneo = lane & 15;
    int bid = blockIdx.x;
    int b  = bid & 7;
    int n  = bid >> 3;          // 0..499
    int o_base = w*32;

    float bgv[2], bbv[2], brv[2], lwv[2], lbv[2];
    #pragma unroll
    for (int nt = 0; nt < 2; ++nt){
        int o = o_base + nt*16 + laneo;
        bgv[nt] = bg[o]; bbv[nt] = btm[o]; brv[nt] = br[o];
        lwv[nt] = lw[o]; lbv[nt] = lb[o];
    }

    // shared conv zero-row (rows -1 and 32 clamp here)
    if (tid < 16){
        s8v z = {0,0,0,0,0,0,0,0};
        *(s8v*)&smem[ZROW + tid*8] = z;
    }

    // ---- phase A: SpMM, 4 independent edge chains. Thread t owns 8 shorts
    //      of the contiguous 4KB window X2b[n*16384 + b*2048 + t*8]; all
    //      gathers are 1KB/wave contiguous, L2-resident in the XCD b-stripe. ----
    {
        int tr = tid >> 3;          // t-row 0..31
        int c8 = tid & 7;           // channel chunk 0..7
        int woff = b*2048 + tid*8;
        float dv = dinv[n];
        float sw = dv*dv;
        float a4[4][8];
        s8v v = *(const s8v*)(X2b + (size_t)n*(BT*64) + woff);
        #pragma unroll
        for (int q = 0; q < 8; ++q){
            a4[0][q] = sw * b2f(v[q]);
            a4[1][q] = 0.f; a4[2][q] = 0.f; a4[3][q] = 0.f;
        }
        int e0 = offs[n], e1 = offs[n+1];
        for (int base = e0; base < e1; base += 4){
            int sn[4]; float wv[4];
            #pragma unroll
            for (int j = 0; j < 4; ++j){
                int idx = base + j;
                bool p = idx < e1;
                sn[j] = p ? csrc[idx] : n;      // clamp to own row
                wv[j] = p ? cw[idx] : 0.f;
            }
            s8v u[4];
            #pragma unroll
            for (int j = 0; j < 4; ++j)
                u[j] = *(const s8v*)(X2b + (size_t)sn[j]*(BT*64) + woff);
            #pragma unroll
            for (int j = 0; j < 4; ++j)
                #pragma unroll
                for (int q = 0; q < 8; ++q)
                    a4[j][q] = fmaf(wv[j], b2f(u[j][q]), a4[j][q]);
        }
        s8v rr;
        #pragma unroll
        for (int q = 0; q < 8; ++q)
            rr[q] = f2bs((a4[0][q] + a4[1][q]) + (a4[2][q] + a4[3][q]));
        *(s8v*)&smem[AGS_BASE + tr*AGROW + c8*8] = rr;
    }

    // GCN B fragments (K=64: 2 k-steps) - issue before barrier to overlap
    s8v bwg[2][2];
    #pragma unroll
    for (int nt = 0; nt < 2; ++nt){
        const short* wp = Wgt + (o_base + nt*16 + laneo)*64 + quad*8;
        bwg[nt][0] = *(const s8v*)wp;
        bwg[nt][1] = *(const s8v*)(wp + 32);
    }
    __syncthreads();

    // ---- stage: GCN GEMM from ags, GELU, write h rows to LDS ----
    #pragma unroll
    for (int m = 0; m < 2; ++m){
        const short* arp = &smem[AGS_BASE + (m*16 + laneo)*AGROW + quad*8];
        s8v a0 = *(const s8v*)arp;
        s8v a1 = *(const s8v*)(arp + 32);
        f4v h0 = {0.f,0.f,0.f,0.f}, h1 = {0.f,0.f,0.f,0.f};
        h0 = __builtin_amdgcn_mfma_f32_16x16x32_bf16(a0, bwg[0][0], h0, 0,0,0);
        h0 = __builtin_amdgcn_mfma_f32_16x16x32_bf16(a1, bwg[0][1], h0, 0,0,0);
        h1 = __builtin_amdgcn_mfma_f32_16x16x32_bf16(a0, bwg[1][0], h1, 0,0,0);
        h1 = __builtin_amdgcn_mfma_f32_16x16x32_bf16(a1, bwg[1][1], h1, 0,0,0);
        #pragma unroll
        for (int r = 0; r < 4; ++r){
            int t = m*16 + quad*4 + r;          // C layout: row=quad*4+r
            short* hrow = &smem[t*HROW];
            hrow[o_base + laneo]      = f2bs(gelu_exact(h0[r] + bgv[0]));
            hrow[o_base + 16 + laneo] = f2bs(gelu_exact(h1[r] + bgv[1]));
        }
    }

    // conv + residual B fragments (loaded late to cut peak VGPR in stage phase)
    s8v breg[2][12], bwr[2][2];
    #pragma unroll
    for (int nt = 0; nt < 2; ++nt){
        int o = o_base + nt*16 + laneo;
        const short* wp = W2 + o*KK + quad*8;
        #pragma unroll
        for (int s = 0; s < 12; ++s)
            breg[nt][s] = *(const s8v*)(wp + s*32);
        const short* wr = Wrt + o*64 + quad*8;
        bwr[nt][0] = *(const s8v*)wr;
        bwr[nt][1] = *(const s8v*)(wr + 32);
    }
    __syncthreads();

    // ---- temporal conv MFMA: 2 m-tiles x 12 K-steps x 2 n-tiles ----
    f4v acc[2][2];
    #pragma unroll
    for (int m = 0; m < 2; ++m)
        #pragma unroll
        for (int nt = 0; nt < 2; ++nt)
            acc[m][nt] = (f4v){0.f,0.f,0.f,0.f};
    #pragma unroll
    for (int m = 0; m < 2; ++m){
        #pragma unroll
        for (int s = 0; s < 12; ++s){
            int k  = s >> 2;
            int i0 = (s & 3) * 32;
            int row = m*16 + laneo + k - 1;     // true time index
            int hb = ((unsigned)row > 31u) ? ZROW : row*HROW;
            s8v a = *(const s8v*)&smem[hb + i0 + quad*8];
            acc[m][0] = __builtin_amdgcn_mfma_f32_16x16x32_bf16(a, breg[0][s], acc[m][0], 0,0,0);
            acc[m][1] = __builtin_amdgcn_mfma_f32_16x16x32_bf16(a, breg[1][s], acc[m][1], 0,0,0);
        }
    }
    // ---- residual GEMM from X2b window (same C layout -> register add) ----
    f4v racc[2][2];
    #pragma unroll
    for (int m = 0; m < 2; ++m)
        #pragma unroll
        for (int nt = 0; nt < 2; ++nt)
            racc[m][nt] = (f4v){0.f,0.f,0.f,0.f};
    const short* xp = X2b + ((size_t)n*BT + b*Tv)*64;
    #pragma unroll
    for (int m = 0; m < 2; ++m){
        const short* xrp = xp + (m*16 + laneo)*64 + quad*8;
        s8v a0 = *(const s8v*)xrp;
        s8v a1 = *(const s8v*)(xrp + 32);
        racc[m][0] = __builtin_amdgcn_mfma_f32_16x16x32_bf16(a0, bwr[0][0], racc[m][0], 0,0,0);
        racc[m][0] = __builtin_amdgcn_mfma_f32_16x16x32_bf16(a1, bwr[0][1], racc[m][0], 0,0,0);
        racc[m][1] = __builtin_amdgcn_mfma_f32_16x16x32_bf16(a0, bwr[1][0], racc[m][1], 0,0,0);
        racc[m][1] = __builtin_amdgcn_mfma_f32_16x16x32_bf16(a1, bwr[1][1], racc[m][1], 0,0,0);
    }
    // ---- epilogue: bias+GELU+residual, LN stats ----
    size_t obase = ((size_t)b*Tv*Nv + n)*Hv;
    float yv[2][2][4];
    float srow[2][4], ssrow[2][4];
    #pragma unroll
    for (int m = 0; m < 2; ++m)
        #pragma unroll
        for (int r = 0; r < 4; ++r){ srow[m][r] = 0.f; ssrow[m][r] = 0.f; }
    #pragma unroll
    for (int m = 0; m < 2; ++m){
        #pragma unroll
        for (int nt = 0; nt < 2; ++nt){
            #pragma unroll
            for (int r = 0; r < 4; ++r){
                float gv = gelu_exact(acc[m][nt][r] + bbv[nt]);
                float y = gv + racc[m][nt][r] + brv[nt];
                yv[m][nt][r] = y;
                srow[m][r] += y; ssrow[m][r] += y*y;
            }
        }
    }
    #pragma unroll
    for (int m = 0; m < 2; ++m)
        #pragma unroll
        for (int r = 0; r < 4; ++r){
            #pragma unroll
            for (int msk = 8; msk >= 1; msk >>= 1){
                srow[m][r]  += __shfl_xor(srow[m][r],  msk, 64);
                ssrow[m][r] += __shfl_xor(ssrow[m][r], msk, 64);
            }
        }
    if (laneo == 0){
        #pragma unroll
        for (int m = 0; m < 2; ++m)
            #pragma unroll
            for (int r = 0; r < 4; ++r){
                int t = m*16 + quad*4 + r;
                red[t][w][0] = srow[m][r];
                red[t][w][1] = ssrow[m][r];
            }
    }
    __syncthreads();
    #pragma unroll
    for (int m = 0; m < 2; ++m){
        #pragma unroll
        for (int r = 0; r < 4; ++r){
            int t = m*16 + quad*4 + r;
            float s  = red[t][0][0] + red[t][1][0] + red[t][2][0] + red[t][3][0];
            float ss = red[t][0][1] + red[t][1][1] + red[t][2][1] + red[t][3][1];
            float mu = s * (1.f/128.f);
            float var = fmaxf(ss * (1.f/128.f) - mu*mu, 0.f);
            float rstd = rsqrtf(var + 1e-5f);
            #pragma unroll
            for (int nt = 0; nt < 2; ++nt){
                int o = o_base + nt*16 + laneo;
                out[obase + (size_t)t*Nv*Hv + o] =
                    (yv[m][nt][r] - mu)*rstd*lwv[nt] + lbv[nt];
            }
        }
    }
}

extern "C" void kernel_launch(void* const* d_in, const int* in_sizes, int n_in,
                              void* d_out, int out_size, void* d_ws, size_t ws_size,
                              hipStream_t stream){
    const float* x   = (const float*)d_in[0];
    const int*   ei  = (const int*)d_in[1];
    const float* ew  = (const float*)d_in[2];
    const float* Wg  = (const float*)d_in[3];
    const float* bg  = (const float*)d_in[4];
    const float* Wtm = (const float*)d_in[5];
    const float* btm = (const float*)d_in[6];
    const float* lw  = (const float*)d_in[7];
    const float* lb  = (const float*)d_in[8];
    const float* Wr  = (const float*)d_in[9];
    const float* br  = (const float*)d_in[10];
    float* out = (float*)d_out;

    char* ws = (char*)d_ws;
    float* dinv = (float*)(ws + 0);            // 2048 B
    int*   offs = (int*)  (ws + 4096);         // 2048 B
    int*   csrc = (int*)  (ws + 8192);         // 32768 B
    float* cwn  = (float*)(ws + 40960);        // 32768 B
    short* W2   = (short*)(ws + 73728);        // 98304 B
    short* Wgt  = (short*)(ws + 172032);       // 16384 B
    short* Wrt  = (short*)(ws + 188416);       // 16384 B
    short* X2b  = (short*)(ws + 204800);       // 16.384 MB

    k_xprep<<<1 + ROWS/64 + 64, 1024, 0, stream>>>(x, X2b, Wtm, Wg, Wr,
                                                   W2, Wgt, Wrt,
                                                   ei, ew, dinv, offs, csrc, cwn);
    k_mega <<<8*Nv, 256, 0, stream>>>(X2b, dinv, offs, csrc, cwn,
                                      W2, Wgt, Wrt,
                                      bg, btm, br, lw, lb, out);
}

// Round 7
// 208.862 us; speedup vs baseline: 1.1380x; 1.0462x over previous
//
#include <hip/hip_runtime.h>
#include <hip/hip_bf16.h>
#include <math.h>

#define Bv 8
#define Tv 32
#define Nv 500
#define Fin 64
#define Hv 128
#define Ev 8000
#define Kv 3
#define BT (Bv*Tv)      /* 256 */
#define ROWS (BT*Nv)    /* 128000 */
#define KK (Kv*Hv)      /* 384: flattened conv K dim */

/* k_mega LDS layout (shorts), ONE node per block. 6792 shorts = 13584 B. */
#define HROW 136            /* h row stride (272B) */
#define ZROW (32*HROW)      /* 4352: single zero row (conv pad) */
#define AGS_BASE (ZROW+HROW)/* 4488 shorts (8976 B, 16B aligned) */
#define AGROW 72            /* AGG row stride (144B, 16B aligned) */
#define SMEM_SHORTS (AGS_BASE + 32*AGROW)  /* 6792 */

typedef __attribute__((ext_vector_type(8))) short s8v;   // 8 bf16 = 4 VGPRs
typedef __attribute__((ext_vector_type(4))) float f4v;   // MFMA acc

// branch-free erf (Abramowitz-Stegun 7.1.26, |err| <= 1.5e-7): rcp + 5 FMA + v_exp.
__device__ __forceinline__ float gelu_exact(float v){
    float t  = v*0.70710678118654752440f;
    float ax = fabsf(t);
    float k  = __builtin_amdgcn_rcpf(fmaf(0.3275911f, ax, 1.0f));
    float p  = k*fmaf(k, fmaf(k, fmaf(k, fmaf(k, 1.061405429f, -1.453152027f),
                                      1.421413741f), -0.284496736f), 0.254829592f);
    float e  = __expf(-ax*ax);
    float er = fmaf(-p, e, 1.0f);           // erf(|t|)
    er = copysignf(er, t);
    return 0.5f*v*(1.0f + er);
}
__device__ __forceinline__ short f2bs(float f){
    union { __hip_bfloat16 h; short s; } u;
    u.h = __float2bfloat16(f);
    return u.s;
}
__device__ __forceinline__ float b2f(short s){
    union { unsigned int i; float f; } u;
    u.i = ((unsigned int)(unsigned short)s) << 16;
    return u.f;
}

// ---- fused: block 0 = graph prep (degree+counts, scan, CSR fill);
//      blocks [1, 2000] = x transpose to bf16; tail 64 blocks = weight prep. ----
__global__ __launch_bounds__(1024) void k_xprep(const float* __restrict__ x,
        short* __restrict__ X2b, const float* __restrict__ W,
        const float* __restrict__ Wg, const float* __restrict__ Wr,
        short* __restrict__ W2, short* __restrict__ Wgt, short* __restrict__ Wrt,
        const int* __restrict__ ei, const float* __restrict__ ew,
        float* __restrict__ dinv, int* __restrict__ offs,
        int* __restrict__ csrc, float* __restrict__ cw){
    __shared__ float sdeg[Nv];
    __shared__ int   scnt[Nv];
    __shared__ float sdv[Nv];
    __shared__ int   scur[Nv];
    __shared__ int   sa[512], sb[512];
    int bid = blockIdx.x;
    int tid = threadIdx.x;
    if (bid == 0){
        // ---- graph prep (1024 threads) ----
        if (tid < Nv){ sdeg[tid] = 1.0f; scnt[tid] = 0; }   // self-loop pre-added
        __syncthreads();
        for (int e = tid; e < Ev; e += 1024){
            int d = ei[Ev + e];
            atomicAdd(&sdeg[d], ew[e]);
            atomicAdd(&scnt[d], 1);
        }
        __syncthreads();
        int c = 0;
        if (tid < Nv){
            float d = sdeg[tid];
            float v = (d > 0.f) ? rsqrtf(d) : 0.f;
            sdv[tid] = v; dinv[tid] = v;
        }
        if (tid < 512){ c = (tid < Nv) ? scnt[tid] : 0; sa[tid] = c; }
        __syncthreads();
        int* s = sa; int* t = sb;
        for (int off = 1; off < 512; off <<= 1){
            int v = 0;
            if (tid < 512){ v = s[tid]; if (tid >= off) v += s[tid - off]; }
            if (tid < 512) t[tid] = v;
            __syncthreads();
            int* tmp = s; s = t; t = tmp;
        }
        if (tid < Nv){ int excl = s[tid] - c; offs[tid] = excl; scur[tid] = excl; }
        if (tid == 0) offs[Nv] = Ev;
        __syncthreads();
        for (int e = tid; e < Ev; e += 1024){
            int sn = ei[e], d = ei[Ev + e];
            int pos = atomicAdd(&scur[d], 1);
            csrc[pos] = sn;
            cw[pos] = sdv[sn]*ew[e]*sdv[d];
        }
    } else if (bid <= ROWS/64){
        // ---- x (bt,n,c) fp32 -> X2b (n, bt*64+c) bf16 ----
        int gid = (bid-1)*1024 + tid;        // one float4; total ROWS*16
        int row = gid >> 4, c4 = gid & 15;
        int bt = row / Nv;
        int n  = row - bt*Nv;
        float4 v = ((const float4*)x)[gid];
        short4 sv;
        sv.x = f2bs(v.x); sv.y = f2bs(v.y); sv.z = f2bs(v.z); sv.w = f2bs(v.w);
        *(short4*)(X2b + (size_t)n*(BT*64) + bt*64 + c4*4) = sv;
    } else {
        int idx = (bid - 1 - ROWS/64)*1024 + tid;
        if (idx < Hv*Hv*Kv){
            int o = idx/(Hv*Kv);
            int rem = idx - o*(Hv*Kv);
            int i = rem/Kv, k = rem - i*Kv;
            W2[o*KK + k*Hv + i] = f2bs(W[idx]);           // W2[o][k*128+i]
        } else if (idx < Hv*Hv*Kv + Hv*64){
            int j = idx - Hv*Hv*Kv;
            int o = j >> 6, k = j & 63;
            Wgt[j] = f2bs(Wg[k*Hv + o]);                  // Wgt[o][k]
        } else if (idx < Hv*Hv*Kv + 2*Hv*64){
            int j = idx - Hv*Hv*Kv - Hv*64;
            int o = j >> 6, k = j & 63;
            Wrt[j] = f2bs(Wr[k*Hv + o]);                  // Wrt[o][k]
        }
    }
}

// ---- mega kernel, ONE node per block (grid 8*500 = 4000):
//   phase A: SpMM, edge loop unrolled x4 (4 gather chains in flight)
//   stage:   GCN GEMM (K=64) -> GELU -> LDS (hs)
//   main:    temporal conv GEMM split into 3 k-taps (32-reg weight slice per
//            tap instead of 96-reg full hold -> occupancy 3->4+ blocks/CU)
//            + residual GEMM (x rows prefetched before conv, T14 style)
//            + bias+GELU+residual+LayerNorm -> out
// block = 4 waves; wave w owns output channels [w*32, w*32+32).
// bid swizzle: b = bid&7 pins one 2MB X2b b-stripe per XCD. 500*8=4000 bijective.
// launch_bounds(256,3): reg budget 170 >= est. peak ~130 (R4 spilled at need
// ~200 under this bound; tap-split cut need well below). Verify via FETCH_SIZE.
__global__ __launch_bounds__(256, 3) void k_mega(
        const short* __restrict__ X2b,
        const float* __restrict__ dinv, const int* __restrict__ offs,
        const int* __restrict__ csrc, const float* __restrict__ cw,
        const short* __restrict__ W2, const short* __restrict__ Wgt,
        const short* __restrict__ Wrt,
        const float* __restrict__ bg, const float* __restrict__ btm,
        const float* __restrict__ br, const float* __restrict__ lw,
        const float* __restrict__ lb, float* __restrict__ out){
    __shared__ short smem[SMEM_SHORTS];
    float (*red)[4][2] = (float(*)[4][2])&smem[AGS_BASE];  // overlay dead ags
    int tid  = threadIdx.x;
    int w    = tid >> 6;
    int lane = tid & 63;
    int quad = lane >> 4;
    int laneo = lane & 15;
    int bid = blockIdx.x;
    int b  = bid & 7;
    int n  = bid >> 3;          // 0..499
    int o_base = w*32;

    float bgv[2], bbv[2], brv[2], lwv[2], lbv[2];
    #pragma unroll
    for (int nt = 0; nt < 2; ++nt){
        int o = o_base + nt*16 + laneo;
        bgv[nt] = bg[o]; bbv[nt] = btm[o]; brv[nt] = br[o];
        lwv[nt] = lw[o]; lbv[nt] = lb[o];
    }

    // shared conv zero-row (rows -1 and 32 clamp here)
    if (tid < 16){
        s8v z = {0,0,0,0,0,0,0,0};
        *(s8v*)&smem[ZROW + tid*8] = z;
    }

    // ---- phase A: SpMM, 4 independent edge chains. Thread t owns 8 shorts
    //      of the contiguous 4KB window X2b[n*16384 + b*2048 + t*8]; all
    //      gathers are 1KB/wave contiguous, L2-resident in the XCD b-stripe. ----
    {
        int tr = tid >> 3;          // t-row 0..31
        int c8 = tid & 7;           // channel chunk 0..7
        int woff = b*2048 + tid*8;
        float dv = dinv[n];
        float sw = dv*dv;
        float a4[4][8];
        s8v v = *(const s8v*)(X2b + (size_t)n*(BT*64) + woff);
        #pragma unroll
        for (int q = 0; q < 8; ++q){
            a4[0][q] = sw * b2f(v[q]);
            a4[1][q] = 0.f; a4[2][q] = 0.f; a4[3][q] = 0.f;
        }
        int e0 = offs[n], e1 = offs[n+1];
        for (int base = e0; base < e1; base += 4){
            int sn[4]; float wv[4];
            #pragma unroll
            for (int j = 0; j < 4; ++j){
                int idx = base + j;
                bool p = idx < e1;
                sn[j] = p ? csrc[idx] : n;      // clamp to own row
                wv[j] = p ? cw[idx] : 0.f;
            }
            s8v u[4];
            #pragma unroll
            for (int j = 0; j < 4; ++j)
                u[j] = *(const s8v*)(X2b + (size_t)sn[j]*(BT*64) + woff);
            #pragma unroll
            for (int j = 0; j < 4; ++j)
                #pragma unroll
                for (int q = 0; q < 8; ++q)
                    a4[j][q] = fmaf(wv[j], b2f(u[j][q]), a4[j][q]);
        }
        s8v rr;
        #pragma unroll
        for (int q = 0; q < 8; ++q)
            rr[q] = f2bs((a4[0][q] + a4[1][q]) + (a4[2][q] + a4[3][q]));
        *(s8v*)&smem[AGS_BASE + tr*AGROW + c8*8] = rr;
    }

    // GCN B fragments (K=64: 2 k-steps) - issue before barrier to overlap
    s8v bwg[2][2];
    #pragma unroll
    for (int nt = 0; nt < 2; ++nt){
        const short* wp = Wgt + (o_base + nt*16 + laneo)*64 + quad*8;
        bwg[nt][0] = *(const s8v*)wp;
        bwg[nt][1] = *(const s8v*)(wp + 32);
    }
    __syncthreads();

    // ---- stage: GCN GEMM from ags, GELU, write h rows to LDS ----
    #pragma unroll
    for (int m = 0; m < 2; ++m){
        const short* arp = &smem[AGS_BASE + (m*16 + laneo)*AGROW + quad*8];
        s8v a0 = *(const s8v*)arp;
        s8v a1 = *(const s8v*)(arp + 32);
        f4v h0 = {0.f,0.f,0.f,0.f}, h1 = {0.f,0.f,0.f,0.f};
        h0 = __builtin_amdgcn_mfma_f32_16x16x32_bf16(a0, bwg[0][0], h0, 0,0,0);
        h0 = __builtin_amdgcn_mfma_f32_16x16x32_bf16(a1, bwg[0][1], h0, 0,0,0);
        h1 = __builtin_amdgcn_mfma_f32_16x16x32_bf16(a0, bwg[1][0], h1, 0,0,0);
        h1 = __builtin_amdgcn_mfma_f32_16x16x32_bf16(a1, bwg[1][1], h1, 0,0,0);
        #pragma unroll
        for (int r = 0; r < 4; ++r){
            int t = m*16 + quad*4 + r;          // C layout: row=quad*4+r
            short* hrow = &smem[t*HROW];
            hrow[o_base + laneo]      = f2bs(gelu_exact(h0[r] + bgv[0]));
            hrow[o_base + 16 + laneo] = f2bs(gelu_exact(h1[r] + bgv[1]));
        }
    }

    // residual B fragments (16 regs; used after conv)
    s8v bwr[2][2];
    #pragma unroll
    for (int nt = 0; nt < 2; ++nt){
        const short* wr = Wrt + (o_base + nt*16 + laneo)*64 + quad*8;
        bwr[nt][0] = *(const s8v*)wr;
        bwr[nt][1] = *(const s8v*)(wr + 32);
    }
    __syncthreads();

    // T14: issue residual x-row loads now; consumed after the conv loop.
    s8v xa[2][2];
    {
        const short* xp = X2b + ((size_t)n*BT + b*Tv)*64;
        #pragma unroll
        for (int m = 0; m < 2; ++m){
            const short* xrp = xp + (m*16 + laneo)*64 + quad*8;
            xa[m][0] = *(const s8v*)xrp;
            xa[m][1] = *(const s8v*)(xrp + 32);
        }
    }

    // ---- temporal conv MFMA: 3 k-taps, 32-reg weight slice per tap.
    //      #pragma unroll 1 keeps the slice loads inside the loop (prevents
    //      re-hoisting back to a 96-reg hold). Per-acc accumulation order
    //      (k asc, j asc) identical to the fused version -> bit-identical. ----
    f4v acc[2][2];
    #pragma unroll
    for (int m = 0; m < 2; ++m)
        #pragma unroll
        for (int nt = 0; nt < 2; ++nt)
            acc[m][nt] = (f4v){0.f,0.f,0.f,0.f};
    #pragma unroll 1
    for (int k = 0; k < 3; ++k){
        s8v bsl[2][4];
        #pragma unroll
        for (int nt = 0; nt < 2; ++nt){
            const short* wp = W2 + (o_base + nt*16 + laneo)*KK + k*128 + quad*8;
            #pragma unroll
            for (int j = 0; j < 4; ++j)
                bsl[nt][j] = *(const s8v*)(wp + j*32);
        }
        #pragma unroll
        for (int m = 0; m < 2; ++m){
            int row = m*16 + laneo + k - 1;     // true time index
            int hb = ((unsigned)row > 31u) ? ZROW : row*HROW;
            #pragma unroll
            for (int j = 0; j < 4; ++j){
                s8v a = *(const s8v*)&smem[hb + j*32 + quad*8];
                acc[m][0] = __builtin_amdgcn_mfma_f32_16x16x32_bf16(a, bsl[0][j], acc[m][0], 0,0,0);
                acc[m][1] = __builtin_amdgcn_mfma_f32_16x16x32_bf16(a, bsl[1][j], acc[m][1], 0,0,0);
            }
        }
    }
    // ---- residual GEMM (operands already in registers) ----
    f4v racc[2][2];
    #pragma unroll
    for (int m = 0; m < 2; ++m)
        #pragma unroll
        for (int nt = 0; nt < 2; ++nt)
            racc[m][nt] = (f4v){0.f,0.f,0.f,0.f};
    #pragma unroll
    for (int m = 0; m < 2; ++m){
        racc[m][0] = __builtin_amdgcn_mfma_f32_16x16x32_bf16(xa[m][0], bwr[0][0], racc[m][0], 0,0,0);
        racc[m][0] = __builtin_amdgcn_mfma_f32_16x16x32_bf16(xa[m][1], bwr[0][1], racc[m][0], 0,0,0);
        racc[m][1] = __builtin_amdgcn_mfma_f32_16x16x32_bf16(xa[m][0], bwr[1][0], racc[m][1], 0,0,0);
        racc[m][1] = __builtin_amdgcn_mfma_f32_16x16x32_bf16(xa[m][1], bwr[1][1], racc[m][1], 0,0,0);
    }
    // ---- epilogue: bias+GELU+residual, LN stats ----
    size_t obase = ((size_t)b*Tv*Nv + n)*Hv;
    float yv[2][2][4];
    float srow[2][4], ssrow[2][4];
    #pragma unroll
    for (int m = 0; m < 2; ++m)
        #pragma unroll
        for (int r = 0; r < 4; ++r){ srow[m][r] = 0.f; ssrow[m][r] = 0.f; }
    #pragma unroll
    for (int m = 0; m < 2; ++m){
        #pragma unroll
        for (int nt = 0; nt < 2; ++nt){
            #pragma unroll
            for (int r = 0; r < 4; ++r){
                float gv = gelu_exact(acc[m][nt][r] + bbv[nt]);
                float y = gv + racc[m][nt][r] + brv[nt];
                yv[m][nt][r] = y;
                srow[m][r] += y; ssrow[m][r] += y*y;
            }
        }
    }
    #pragma unroll
    for (int m = 0; m < 2; ++m)
        #pragma unroll
        for (int r = 0; r < 4; ++r){
            #pragma unroll
            for (int msk = 8; msk >= 1; msk >>= 1){
                srow[m][r]  += __shfl_xor(srow[m][r],  msk, 64);
                ssrow[m][r] += __shfl_xor(ssrow[m][r], msk, 64);
            }
        }
    if (laneo == 0){
        #pragma unroll
        for (int m = 0; m < 2; ++m)
            #pragma unroll
            for (int r = 0; r < 4; ++r){
                int t = m*16 + quad*4 + r;
                red[t][w][0] = srow[m][r];
                red[t][w][1] = ssrow[m][r];
            }
    }
    __syncthreads();
    #pragma unroll
    for (int m = 0; m < 2; ++m){
        #pragma unroll
        for (int r = 0; r < 4; ++r){
            int t = m*16 + quad*4 + r;
            float s  = red[t][0][0] + red[t][1][0] + red[t][2][0] + red[t][3][0];
            float ss = red[t][0][1] + red[t][1][1] + red[t][2][1] + red[t][3][1];
            float mu = s * (1.f/128.f);
            float var = fmaxf(ss * (1.f/128.f) - mu*mu, 0.f);
            float rstd = rsqrtf(var + 1e-5f);
            #pragma unroll
            for (int nt = 0; nt < 2; ++nt){
                int o = o_base + nt*16 + laneo;
                out[obase + (size_t)t*Nv*Hv + o] =
                    (yv[m][nt][r] - mu)*rstd*lwv[nt] + lbv[nt];
            }
        }
    }
}

extern "C" void kernel_launch(void* const* d_in, const int* in_sizes, int n_in,
                              void* d_out, int out_size, void* d_ws, size_t ws_size,
                              hipStream_t stream){
    const float* x   = (const float*)d_in[0];
    const int*   ei  = (const int*)d_in[1];
    const float* ew  = (const float*)d_in[2];
    const float* Wg  = (const float*)d_in[3];
    const float* bg  = (const float*)d_in[4];
    const float* Wtm = (const float*)d_in[5];
    const float* btm = (const float*)d_in[6];
    const float* lw  = (const float*)d_in[7];
    const float* lb  = (const float*)d_in[8];
    const float* Wr  = (const float*)d_in[9];
    const float* br  = (const float*)d_in[10];
    float* out = (float*)d_out;

    char* ws = (char*)d_ws;
    float* dinv = (float*)(ws + 0);            // 2048 B
    int*   offs = (int*)  (ws + 4096);         // 2048 B
    int*   csrc = (int*)  (ws + 8192);         // 32768 B
    float* cwn  = (float*)(ws + 40960);        // 32768 B
    short* W2   = (short*)(ws + 73728);        // 98304 B
    short* Wgt  = (short*)(ws + 172032);       // 16384 B
    short* Wrt  = (short*)(ws + 188416);       // 16384 B
    short* X2b  = (short*)(ws + 204800);       // 16.384 MB

    k_xprep<<<1 + ROWS/64 + 64, 1024, 0, stream>>>(x, X2b, Wtm, Wg, Wr,
                                                   W2, Wgt, Wrt,
                                                   ei, ew, dinv, offs, csrc, cwn);
    k_mega <<<8*Nv, 256, 0, stream>>>(X2b, dinv, offs, csrc, cwn,
                                      W2, Wgt, Wrt,
                                      bg, btm, br, lw, lb, out);
}